// Round 3
// baseline (767.219 us; speedup 1.0000x reference)
//
#include <hip/hip_runtime.h>
#include <cfloat>
#include <cmath>

// Pipeline: (1) fused reflection-pad + adaptive max pool 3D -> pooled (B,S=256,C=32) in ws
//           (2) tiny attention + log_softmax -> out (B,32)
//
// Pad+pool collapses to plain max over input-coord windows:
//   H/W: [0,15],[15,31],[31,47],[47,63],[64,80],[80,96],[96,112],[112,127]
//   D:   [0,7],[7,15],[16,24],[24,31]
// Grid: (b, c, d-half{0..15|16..31}, h-half{0..63|64..127}) -> 1024 blocks, no cross-block cells.
//
// Lane map (coalescing-first): thread t owns float4 chunk c=t&31 of row r=t>>5.
// A wave's load = 64 consecutive float4 = 1 KiB contiguous (16 lines/instr, minimum).
// Window bookkeeping is per-thread in registers:
//   - core chunk c -> ow = c>>2 (chunks 0..3 == window [0,15] exactly, etc.)
//   - boundary COLS: c in {3,7,11}: .w (cols 15/31/47) also feeds ow+1;
//                    c in {20,24,28}: .x (cols 80/96/112) also feeds ow-1.
//   - boundary ROWS: g_h=0 rows 15/31/47 (k in {1,3,5}, r==7) also feed oh+1;
//                    g_h=1 rows 80/96/112 (k in {2,4,6}, r==0) also feed oh-1.
//   - d windows: A = (dl<=lim), B = (dl>=lim), lim = 7+g_d (plane lim feeds both).
// Final: one LDS atomicMax flush per accumulator (order-preserving uint keys).

__device__ inline unsigned fkey(float f) {
    unsigned u = __float_as_uint(f);
    return (u & 0x80000000u) ? ~u : (u | 0x80000000u);   // order-preserving float->uint
}
__device__ inline float funkey(unsigned k) {
    return __uint_as_float((k & 0x80000000u) ? (k ^ 0x80000000u) : ~k);
}
__device__ inline float max4(float4 v) { return fmaxf(fmaxf(v.x, v.y), fmaxf(v.z, v.w)); }

__global__ __launch_bounds__(256) void pool_kernel(const float* __restrict__ x,
                                                   float* __restrict__ pooled) {
    const int blk = blockIdx.x;
    const int g_h = blk & 1;          // h-half: rows [0,63] or [64,127]
    const int g_d = (blk >> 1) & 1;   // d-half: planes [0,15] or [16,31]
    const int bc  = blk >> 2;         // b*32 + c
    const int t = threadIdx.x;
    const int c = t & 31;             // float4 chunk in row (cols 4c..4c+3)
    const int r = t >> 5;             // row offset 0..7

    __shared__ unsigned accK[2][4][8];          // [od_local][oh_local][ow]
    if (t < 64) ((unsigned*)accK)[t] = 0u;      // 0 < fkey(any value we store)

    const float4* px = (const float4*)(x + ((size_t)bc * 32 + (size_t)g_d * 16) * 16384
                                         + (size_t)g_h * 64 * 128)
                       + (size_t)(r * 32 + c);
    const int lim = 7 + g_d;          // plane 'lim' is in both local d-windows

    const bool hasW = (c == 3 || c == 7 || c == 11);    // edge col -> ow+1
    const bool hasX = (c == 20 || c == 24 || c == 28);  // edge col -> ow-1
    const bool hasE = hasW || hasX;

    float accA[4], accB[4], eA[4], eB[4];
    #pragma unroll
    for (int i = 0; i < 4; ++i) { accA[i] = -FLT_MAX; accB[i] = -FLT_MAX;
                                  eA[i]   = -FLT_MAX; eB[i]   = -FLT_MAX; }

    for (int dl = 0; dl < 16; ++dl) {
        const float4* p = px + (size_t)dl * 4096;   // plane stride 128*128/4 float4s
        float4 v[8];
        #pragma unroll
        for (int k = 0; k < 8; ++k) v[k] = p[k * 256];   // 8 rows apart (8*128/4)
        const bool m0 = (dl <= lim), m1 = (dl >= lim);

        #pragma unroll
        for (int k = 0; k < 8; ++k) {
            const int oh = k >> 1;                 // rows 8k..8k+7 lie in one oh window
            const float m  = max4(v[k]);
            const float ev = hasW ? v[k].w : v[k].x;
            if (m0) { accA[oh] = fmaxf(accA[oh], m); if (hasE) eA[oh] = fmaxf(eA[oh], ev); }
            if (m1) { accB[oh] = fmaxf(accB[oh], m); if (hasE) eB[oh] = fmaxf(eB[oh], ev); }

            if (g_h == 0) {
                if ((k & 1) == 1 && k < 7 && r == 7) {   // local rows 15,31,47
                    if (m0) { accA[oh+1] = fmaxf(accA[oh+1], m); if (hasE) eA[oh+1] = fmaxf(eA[oh+1], ev); }
                    if (m1) { accB[oh+1] = fmaxf(accB[oh+1], m); if (hasE) eB[oh+1] = fmaxf(eB[oh+1], ev); }
                }
            } else {
                if ((k & 1) == 0 && k > 0 && r == 0) {   // global rows 80,96,112
                    if (m0) { accA[oh-1] = fmaxf(accA[oh-1], m); if (hasE) eA[oh-1] = fmaxf(eA[oh-1], ev); }
                    if (m1) { accB[oh-1] = fmaxf(accB[oh-1], m); if (hasE) eB[oh-1] = fmaxf(eB[oh-1], ev); }
                }
            }
        }
    }
    __syncthreads();   // accK init visible to all

    const int ow = c >> 2;
    #pragma unroll
    for (int oh = 0; oh < 4; ++oh) {
        atomicMax(&accK[0][oh][ow], fkey(accA[oh]));
        atomicMax(&accK[1][oh][ow], fkey(accB[oh]));
    }
    if (hasE) {
        const int owe = hasW ? (ow + 1) : (ow - 1);
        #pragma unroll
        for (int oh = 0; oh < 4; ++oh) {
            atomicMax(&accK[0][oh][owe], fkey(eA[oh]));
            atomicMax(&accK[1][oh][owe], fkey(eB[oh]));
        }
    }
    __syncthreads();

    if (t < 64) {
        const int odl = t >> 5, ohl = (t >> 3) & 3, oww = t & 7;
        const float v = funkey(accK[odl][ohl][oww]);
        const int b = bc >> 5, ch = bc & 31;
        const int s = (g_d * 2 + odl) * 64 + (g_h * 4 + ohl) * 8 + oww;
        pooled[((size_t)b * 256 + s) * 32 + ch] = v;
    }
}

__global__ __launch_bounds__(256) void attn_kernel(const float* __restrict__ pooled,
                                                   const float* __restrict__ Wp,
                                                   const float* __restrict__ Wf,
                                                   const float* __restrict__ bfin,
                                                   float* __restrict__ out) {
    const int b = blockIdx.x;
    const int t = threadIdx.x;          // t == s (0..255)
    const int lane = t & 63, wave = t >> 6;
    __shared__ float sWp[1024];
    __shared__ float part[4][32];
    __shared__ float sctx[32];
    __shared__ float sw[32];
    __shared__ float red[4];

    for (int i = t; i < 1024; i += 256) sWp[i] = Wp[i];
    __syncthreads();

    float xf[32];
    #pragma unroll
    for (int c2 = 0; c2 < 32; ++c2) xf[c2] = pooled[(size_t)b * 8192 + t * 32 + c2];

    // x_proj[s][d] = sum_c xf[c] * Wp[d][c]
    float xp[32];
    #pragma unroll
    for (int d2 = 0; d2 < 32; ++d2) {
        float s = 0.f;
        #pragma unroll
        for (int c2 = 0; c2 < 32; ++c2) s += xf[c2] * sWp[d2 * 32 + c2];
        xp[d2] = s;
    }

    // context[d] = mean_s x_proj[s][d]
    #pragma unroll
    for (int d2 = 0; d2 < 32; ++d2) {
        float v = xp[d2];
        for (int off = 32; off >= 1; off >>= 1) v += __shfl_xor(v, off, 64);
        if (lane == 0) part[wave][d2] = v;
    }
    __syncthreads();
    if (t < 32) sctx[t] = (part[0][t] + part[1][t] + part[2][t] + part[3][t]) * (1.0f / 256.0f);
    __syncthreads();

    // att_logits[s] = dot(context, x_proj[s]); softmax over s
    float l = 0.f;
    #pragma unroll
    for (int c2 = 0; c2 < 32; ++c2) l += sctx[c2] * xp[c2];
    float v = l;
    for (int off = 32; off >= 1; off >>= 1) v = fmaxf(v, __shfl_xor(v, off, 64));
    if (lane == 0) red[wave] = v;
    __syncthreads();
    const float M = fmaxf(fmaxf(red[0], red[1]), fmaxf(red[2], red[3]));
    const float e = expf(l - M);
    v = e;
    for (int off = 32; off >= 1; off >>= 1) v += __shfl_xor(v, off, 64);
    __syncthreads();
    if (lane == 0) red[wave] = v;
    __syncthreads();
    const float S = red[0] + red[1] + red[2] + red[3];
    const float att = e / S;

    // weighted[c] = sum_s att[s] * x_proj[s][c]
    #pragma unroll
    for (int d2 = 0; d2 < 32; ++d2) {
        float w = att * xp[d2];
        for (int off = 32; off >= 1; off >>= 1) w += __shfl_xor(w, off, 64);
        if (lane == 0) part[wave][d2] = w;
    }
    __syncthreads();
    if (t < 32) sw[t] = part[0][t] + part[1][t] + part[2][t] + part[3][t];
    __syncthreads();

    // channel_logits = weighted @ Wf^T + bf; log_softmax over 32 channels
    if (t < 32) {
        float logit = bfin[t];
        #pragma unroll
        for (int k = 0; k < 32; ++k) logit += sw[k] * Wf[t * 32 + k];
        float m2 = logit;
        for (int off = 16; off >= 1; off >>= 1) m2 = fmaxf(m2, __shfl_xor(m2, off, 32));
        const float e2 = expf(logit - m2);
        float s2 = e2;
        for (int off = 16; off >= 1; off >>= 1) s2 += __shfl_xor(s2, off, 32);
        out[b * 32 + t] = logit - m2 - logf(s2);
    }
}

extern "C" void kernel_launch(void* const* d_in, const int* in_sizes, int n_in,
                              void* d_out, int out_size, void* d_ws, size_t ws_size,
                              hipStream_t stream) {
    const float* x  = (const float*)d_in[0];
    const float* Wp = (const float*)d_in[1];
    const float* Wf = (const float*)d_in[2];
    const float* bf = (const float*)d_in[3];
    float* out = (float*)d_out;
    float* pooled = (float*)d_ws;   // (8,256,32) fp32 = 256 KiB

    pool_kernel<<<dim3(1024), dim3(256), 0, stream>>>(x, pooled);
    attn_kernel<<<dim3(8), dim3(256), 0, stream>>>(pooled, Wp, Wf, bf, out);
}